// Round 1
// baseline (11680.100 us; speedup 1.0000x reference)
//
#include <hip/hip_runtime.h>
#include <hip/hip_bf16.h>
#include <math.h>

#define BATCH 256
#define SEQN  256
#define INDIM 128
#define HID   512
#define MID   256
#define KMAX  4
#define NCLS  16

// ---------------------------------------------------------------------------
// Phase 1: for gate g in {z(0), r(1)}:
//   pre[b,j] = bias[j] + sum_k h[b,k]*U[k,j] + sum_i x[b,t,i]*W[i,j]
//   g==0: z[b,j] = hard_sigmoid(pre)
//   g==1: r = hard_sigmoid(pre); v[b,j] = r * h[b,j]
// 32x32 tile per block, 256 threads, 2x2 per thread. K = 512 (h@U) + 128 (x@W).
// ---------------------------------------------------------------------------
__global__ __launch_bounds__(256) void gru_phase1(
    const float* __restrict__ h, const float* __restrict__ x,
    const float* __restrict__ Uz, const float* __restrict__ Ur,
    const float* __restrict__ Wz, const float* __restrict__ Wr,
    const float* __restrict__ bz, const float* __restrict__ br,
    float* __restrict__ zbuf, float* __restrict__ vbuf, int t)
{
    const int jt = blockIdx.x;   // 0..15
    const int bt = blockIdx.y;   // 0..7
    const int gate = blockIdx.z; // 0..1
    const float* __restrict__ U = gate ? Ur : Uz;
    const float* __restrict__ W = gate ? Wr : Wz;
    const float* __restrict__ bias = gate ? br : bz;

    __shared__ float sA[32][33];   // sA[kk][row]
    __shared__ float sB[32][33];   // sB[kk][col]

    const int tid = threadIdx.x;
    const int tx = tid & 15, ty = tid >> 4;
    const int b0 = bt * 32, j0 = jt * 32;
    const int lr = tid >> 3, lk4 = (tid & 7) << 2;

    float acc[2][2] = {{0.f,0.f},{0.f,0.f}};

    for (int kt = 0; kt < 20; ++kt) {
        const int k0 = kt * 32;
        float4 a, bv;
        if (kt < 16) {
            a  = *reinterpret_cast<const float4*>(&h[(b0 + lr) * HID + k0 + lk4]);
            bv = *reinterpret_cast<const float4*>(&U[(k0 + lr) * HID + j0 + lk4]);
        } else {
            const int i0 = k0 - HID;
            a  = *reinterpret_cast<const float4*>(&x[((size_t)(b0 + lr) * SEQN + t) * INDIM + i0 + lk4]);
            bv = *reinterpret_cast<const float4*>(&W[(i0 + lr) * HID + j0 + lk4]);
        }
        __syncthreads();
        sA[lk4+0][lr] = a.x; sA[lk4+1][lr] = a.y; sA[lk4+2][lr] = a.z; sA[lk4+3][lr] = a.w;
        sB[lr][lk4+0] = bv.x; sB[lr][lk4+1] = bv.y; sB[lr][lk4+2] = bv.z; sB[lr][lk4+3] = bv.w;
        __syncthreads();
        #pragma unroll
        for (int kk = 0; kk < 32; ++kk) {
            float a0 = sA[kk][ty*2], a1 = sA[kk][ty*2+1];
            float w0 = sB[kk][tx*2], w1 = sB[kk][tx*2+1];
            acc[0][0] += a0*w0; acc[0][1] += a0*w1;
            acc[1][0] += a1*w0; acc[1][1] += a1*w1;
        }
    }

    #pragma unroll
    for (int q = 0; q < 2; ++q) {
        #pragma unroll
        for (int c = 0; c < 2; ++c) {
            const int row = b0 + ty*2 + q, col = j0 + tx*2 + c;
            float pre = acc[q][c] + bias[col];
            float g = fminf(fmaxf(0.2f * pre + 0.5f, 0.f), 1.f);
            if (gate == 0) {
                zbuf[row * HID + col] = g;
            } else {
                vbuf[row * HID + col] = g * h[row * HID + col];
            }
        }
    }
}

// ---------------------------------------------------------------------------
// Phase 2: hh = tanh(b_h + v@U_h + x_t@W_h);  h = z*h + (1-z)*hh  (in place)
// ---------------------------------------------------------------------------
__global__ __launch_bounds__(256) void gru_phase2(
    float* __restrict__ h, const float* __restrict__ x,
    const float* __restrict__ v, const float* __restrict__ z,
    const float* __restrict__ Uh, const float* __restrict__ Wh,
    const float* __restrict__ bh, int t)
{
    const int jt = blockIdx.x, bt = blockIdx.y;
    __shared__ float sA[32][33];
    __shared__ float sB[32][33];
    const int tid = threadIdx.x;
    const int tx = tid & 15, ty = tid >> 4;
    const int b0 = bt * 32, j0 = jt * 32;
    const int lr = tid >> 3, lk4 = (tid & 7) << 2;

    float acc[2][2] = {{0.f,0.f},{0.f,0.f}};

    for (int kt = 0; kt < 20; ++kt) {
        const int k0 = kt * 32;
        float4 a, bv;
        if (kt < 16) {
            a  = *reinterpret_cast<const float4*>(&v[(b0 + lr) * HID + k0 + lk4]);
            bv = *reinterpret_cast<const float4*>(&Uh[(k0 + lr) * HID + j0 + lk4]);
        } else {
            const int i0 = k0 - HID;
            a  = *reinterpret_cast<const float4*>(&x[((size_t)(b0 + lr) * SEQN + t) * INDIM + i0 + lk4]);
            bv = *reinterpret_cast<const float4*>(&Wh[(i0 + lr) * HID + j0 + lk4]);
        }
        __syncthreads();
        sA[lk4+0][lr] = a.x; sA[lk4+1][lr] = a.y; sA[lk4+2][lr] = a.z; sA[lk4+3][lr] = a.w;
        sB[lr][lk4+0] = bv.x; sB[lr][lk4+1] = bv.y; sB[lr][lk4+2] = bv.z; sB[lr][lk4+3] = bv.w;
        __syncthreads();
        #pragma unroll
        for (int kk = 0; kk < 32; ++kk) {
            float a0 = sA[kk][ty*2], a1 = sA[kk][ty*2+1];
            float w0 = sB[kk][tx*2], w1 = sB[kk][tx*2+1];
            acc[0][0] += a0*w0; acc[0][1] += a0*w1;
            acc[1][0] += a1*w0; acc[1][1] += a1*w1;
        }
    }

    #pragma unroll
    for (int q = 0; q < 2; ++q) {
        #pragma unroll
        for (int c = 0; c < 2; ++c) {
            const int row = b0 + ty*2 + q, col = j0 + tx*2 + c;
            float hh = tanhf(acc[q][c] + bh[col]);
            float zz = z[row * HID + col];
            float ho = h[row * HID + col];
            h[row * HID + col] = zz * ho + (1.f - zz) * hh;
        }
    }
}

// ---------------------------------------------------------------------------
// Maxout: m[b,o] = max_p ( mo_b[p,o] + sum_i h[b,i] * mo_W[p,i,o] )
// ---------------------------------------------------------------------------
__global__ __launch_bounds__(256) void maxout_k(
    const float* __restrict__ h, const float* __restrict__ moW,
    const float* __restrict__ mob, float* __restrict__ m)
{
    const int ot = blockIdx.x, bt = blockIdx.y;  // 8 x 8
    __shared__ float sA[32][33];
    __shared__ float sB[4][32][33];
    const int tid = threadIdx.x;
    const int tx = tid & 15, ty = tid >> 4;
    const int b0 = bt * 32, o0 = ot * 32;
    const int lr = tid >> 3, lk4 = (tid & 7) << 2;

    float acc[4][2][2];
    #pragma unroll
    for (int p = 0; p < 4; ++p)
        acc[p][0][0] = acc[p][0][1] = acc[p][1][0] = acc[p][1][1] = 0.f;

    for (int kt = 0; kt < 16; ++kt) {
        const int k0 = kt * 32;
        float4 a = *reinterpret_cast<const float4*>(&h[(b0 + lr) * HID + k0 + lk4]);
        float4 w[4];
        #pragma unroll
        for (int p = 0; p < 4; ++p)
            w[p] = *reinterpret_cast<const float4*>(&moW[((size_t)p * HID + k0 + lr) * MID + o0 + lk4]);
        __syncthreads();
        sA[lk4+0][lr] = a.x; sA[lk4+1][lr] = a.y; sA[lk4+2][lr] = a.z; sA[lk4+3][lr] = a.w;
        #pragma unroll
        for (int p = 0; p < 4; ++p) {
            sB[p][lr][lk4+0] = w[p].x; sB[p][lr][lk4+1] = w[p].y;
            sB[p][lr][lk4+2] = w[p].z; sB[p][lr][lk4+3] = w[p].w;
        }
        __syncthreads();
        #pragma unroll
        for (int kk = 0; kk < 32; ++kk) {
            float a0 = sA[kk][ty*2], a1 = sA[kk][ty*2+1];
            #pragma unroll
            for (int p = 0; p < 4; ++p) {
                float w0 = sB[p][kk][tx*2], w1 = sB[p][kk][tx*2+1];
                acc[p][0][0] += a0*w0; acc[p][0][1] += a0*w1;
                acc[p][1][0] += a1*w0; acc[p][1][1] += a1*w1;
            }
        }
    }

    #pragma unroll
    for (int q = 0; q < 2; ++q) {
        #pragma unroll
        for (int c = 0; c < 2; ++c) {
            const int row = b0 + ty*2 + q, col = o0 + tx*2 + c;
            float best = -1e30f;
            #pragma unroll
            for (int p = 0; p < 4; ++p)
                best = fmaxf(best, acc[p][q][c] + mob[p * MID + col]);
            m[row * MID + col] = best;
        }
    }
}

// ---------------------------------------------------------------------------
// Dense1 (linear): a1 = m @ d1_W + d1_b      [256,256]x[256,256]
// ---------------------------------------------------------------------------
__global__ __launch_bounds__(256) void dense1_k(
    const float* __restrict__ m, const float* __restrict__ W,
    const float* __restrict__ b, float* __restrict__ a1)
{
    const int jt = blockIdx.x, bt = blockIdx.y;
    __shared__ float sA[32][33];
    __shared__ float sB[32][33];
    const int tid = threadIdx.x;
    const int tx = tid & 15, ty = tid >> 4;
    const int b0 = bt * 32, j0 = jt * 32;
    const int lr = tid >> 3, lk4 = (tid & 7) << 2;

    float acc[2][2] = {{0.f,0.f},{0.f,0.f}};

    for (int kt = 0; kt < 8; ++kt) {
        const int k0 = kt * 32;
        float4 a  = *reinterpret_cast<const float4*>(&m[(b0 + lr) * MID + k0 + lk4]);
        float4 bv = *reinterpret_cast<const float4*>(&W[(k0 + lr) * MID + j0 + lk4]);
        __syncthreads();
        sA[lk4+0][lr] = a.x; sA[lk4+1][lr] = a.y; sA[lk4+2][lr] = a.z; sA[lk4+3][lr] = a.w;
        sB[lr][lk4+0] = bv.x; sB[lr][lk4+1] = bv.y; sB[lr][lk4+2] = bv.z; sB[lr][lk4+3] = bv.w;
        __syncthreads();
        #pragma unroll
        for (int kk = 0; kk < 32; ++kk) {
            float a0 = sA[kk][ty*2], a1v = sA[kk][ty*2+1];
            float w0 = sB[kk][tx*2], w1 = sB[kk][tx*2+1];
            acc[0][0] += a0*w0; acc[0][1] += a0*w1;
            acc[1][0] += a1v*w0; acc[1][1] += a1v*w1;
        }
    }

    #pragma unroll
    for (int q = 0; q < 2; ++q)
        #pragma unroll
        for (int c = 0; c < 2; ++c) {
            const int row = b0 + ty*2 + q, col = j0 + tx*2 + c;
            a1[row * MID + col] = acc[q][c] + b[col];
        }
}

// ---------------------------------------------------------------------------
// Highway: t = sigmoid(a1@hw_Wc + hw_bc); hh = relu(a1@hw_W + hw_b);
//          h2 = t*hh + (1-t)*a1
// ---------------------------------------------------------------------------
__global__ __launch_bounds__(256) void highway_k(
    const float* __restrict__ a1,
    const float* __restrict__ hwW, const float* __restrict__ hwb,
    const float* __restrict__ hwWc, const float* __restrict__ hwbc,
    float* __restrict__ h2)
{
    const int jt = blockIdx.x, bt = blockIdx.y;
    __shared__ float sA[32][33];
    __shared__ float sBh[32][33];
    __shared__ float sBc[32][33];
    const int tid = threadIdx.x;
    const int tx = tid & 15, ty = tid >> 4;
    const int b0 = bt * 32, j0 = jt * 32;
    const int lr = tid >> 3, lk4 = (tid & 7) << 2;

    float acch[2][2] = {{0.f,0.f},{0.f,0.f}};
    float accc[2][2] = {{0.f,0.f},{0.f,0.f}};

    for (int kt = 0; kt < 8; ++kt) {
        const int k0 = kt * 32;
        float4 a   = *reinterpret_cast<const float4*>(&a1[(b0 + lr) * MID + k0 + lk4]);
        float4 bh4 = *reinterpret_cast<const float4*>(&hwW[(k0 + lr) * MID + j0 + lk4]);
        float4 bc4 = *reinterpret_cast<const float4*>(&hwWc[(k0 + lr) * MID + j0 + lk4]);
        __syncthreads();
        sA[lk4+0][lr] = a.x; sA[lk4+1][lr] = a.y; sA[lk4+2][lr] = a.z; sA[lk4+3][lr] = a.w;
        sBh[lr][lk4+0] = bh4.x; sBh[lr][lk4+1] = bh4.y; sBh[lr][lk4+2] = bh4.z; sBh[lr][lk4+3] = bh4.w;
        sBc[lr][lk4+0] = bc4.x; sBc[lr][lk4+1] = bc4.y; sBc[lr][lk4+2] = bc4.z; sBc[lr][lk4+3] = bc4.w;
        __syncthreads();
        #pragma unroll
        for (int kk = 0; kk < 32; ++kk) {
            float a0 = sA[kk][ty*2], a1v = sA[kk][ty*2+1];
            float h0 = sBh[kk][tx*2], h1 = sBh[kk][tx*2+1];
            float c0 = sBc[kk][tx*2], c1 = sBc[kk][tx*2+1];
            acch[0][0] += a0*h0; acch[0][1] += a0*h1;
            acch[1][0] += a1v*h0; acch[1][1] += a1v*h1;
            accc[0][0] += a0*c0; accc[0][1] += a0*c1;
            accc[1][0] += a1v*c0; accc[1][1] += a1v*c1;
        }
    }

    #pragma unroll
    for (int q = 0; q < 2; ++q)
        #pragma unroll
        for (int c = 0; c < 2; ++c) {
            const int row = b0 + ty*2 + q, col = j0 + tx*2 + c;
            float tt = 1.f / (1.f + expf(-(accc[q][c] + hwbc[col])));
            float hp = fmaxf(acch[q][c] + hwb[col], 0.f);
            float av = a1[row * MID + col];
            h2[row * MID + col] = tt * hp + (1.f - tt) * av;
        }
}

// ---------------------------------------------------------------------------
// d2 + softmax: out = softmax(h2 @ d2_W + d2_b), NCLS=16.
// 256 threads = 16 rows x 16 classes per block; shuffle softmax (width 16).
// ---------------------------------------------------------------------------
__global__ __launch_bounds__(256) void d2_softmax(
    const float* __restrict__ h2, const float* __restrict__ W,
    const float* __restrict__ b, float* __restrict__ out)
{
    const int b0 = blockIdx.x * 16;
    const int r = threadIdx.x >> 4, c = threadIdx.x & 15;
    const int row = b0 + r;

    float acc = b[c];
    for (int i = 0; i < MID; ++i)
        acc += h2[row * MID + i] * W[i * NCLS + c];

    float mx = acc;
    #pragma unroll
    for (int off = 8; off; off >>= 1)
        mx = fmaxf(mx, __shfl_xor(mx, off, 16));
    float e = expf(acc - mx);
    float s = e;
    #pragma unroll
    for (int off = 8; off; off >>= 1)
        s += __shfl_xor(s, off, 16);
    out[row * NCLS + c] = e / s;
}

// ---------------------------------------------------------------------------
extern "C" void kernel_launch(void* const* d_in, const int* in_sizes, int n_in,
                              void* d_out, int out_size, void* d_ws, size_t ws_size,
                              hipStream_t stream) {
    (void)in_sizes; (void)n_in; (void)out_size; (void)ws_size;

    const float* x    = (const float*)d_in[0];
    const float* Wz   = (const float*)d_in[1];
    const float* Wr   = (const float*)d_in[2];
    const float* Wh   = (const float*)d_in[3];
    const float* Uz   = (const float*)d_in[4];
    const float* Ur   = (const float*)d_in[5];
    const float* Uh   = (const float*)d_in[6];
    const float* bz   = (const float*)d_in[7];
    const float* br   = (const float*)d_in[8];
    const float* bh   = (const float*)d_in[9];
    const float* moW  = (const float*)d_in[10];
    const float* mob  = (const float*)d_in[11];
    const float* d1W  = (const float*)d_in[12];
    const float* d1b  = (const float*)d_in[13];
    const float* hwW  = (const float*)d_in[14];
    const float* hwb  = (const float*)d_in[15];
    const float* hwWc = (const float*)d_in[16];
    const float* hwbc = (const float*)d_in[17];
    const float* d2W  = (const float*)d_in[18];
    const float* d2b  = (const float*)d_in[19];
    float* out = (float*)d_out;

    char* ws = (char*)d_ws;
    float* h  = (float*)(ws + 0x000000);   // 512 KB  [256,512]
    float* v  = (float*)(ws + 0x080000);   // 512 KB
    float* z  = (float*)(ws + 0x100000);   // 512 KB
    float* mx = (float*)(ws + 0x180000);   // 256 KB  [256,256]
    float* a1 = (float*)(ws + 0x1C0000);   // 256 KB
    float* h2 = (float*)(ws + 0x200000);   // 256 KB

    hipMemsetAsync(h, 0, BATCH * HID * sizeof(float), stream);

    dim3 blk(256);
    for (int t = 0; t < SEQN; ++t) {
        gru_phase1<<<dim3(16, 8, 2), blk, 0, stream>>>(h, x, Uz, Ur, Wz, Wr, bz, br, z, v, t);
        gru_phase2<<<dim3(16, 8), blk, 0, stream>>>(h, x, v, z, Uh, Wh, bh, t);
    }
    maxout_k<<<dim3(8, 8), blk, 0, stream>>>(h, moW, mob, mx);
    dense1_k<<<dim3(8, 8), blk, 0, stream>>>(mx, d1W, d1b, a1);
    highway_k<<<dim3(8, 8), blk, 0, stream>>>(a1, hwW, hwb, hwWc, hwbc, h2);
    d2_softmax<<<16, blk, 0, stream>>>(h2, d2W, d2b, out);
}

// Round 2
// 3964.264 us; speedup vs baseline: 2.9463x; 2.9463x over previous
//
#include <hip/hip_runtime.h>
#include <hip/hip_bf16.h>
#include <math.h>

#define BATCH 256
#define SEQN  256
#define INDIM 128
#define HID   512
#define MID   256
#define NCLS  16

typedef _Float16 half8 __attribute__((ext_vector_type(8)));
typedef float    f32x4 __attribute__((ext_vector_type(4)));

// ---------------------------------------------------------------------------
// Weight pre-pack into MFMA-B fragment layout for v_mfma_f32_16x16x32_f16:
//   B-frag: lane l holds B[k = kt*32 + (l>>4)*8 + j][n = nt*16 + (l&15)], j=0..7
// Pack:  out[((kt*NT + nt)*64 + lane)*8 + j]
// Phase-A pack (z|r combined, NT=64 n-tiles = 1024 cols): k<512 -> U_z/U_r,
// k>=512 -> W_z/W_r (x part).  Phase-B pack (NT=32): U_h / W_h.
// ---------------------------------------------------------------------------
__global__ __launch_bounds__(256) void pack_zr(
    const float* __restrict__ Uz, const float* __restrict__ Ur,
    const float* __restrict__ Wz, const float* __restrict__ Wr,
    _Float16* __restrict__ out)
{
    int idx = blockIdx.x * 256 + threadIdx.x;          // < 20*64*64*8 = 655360
    int j = idx & 7, lane = (idx >> 3) & 63, nt = (idx >> 9) & 63, kt = idx >> 15;
    int k = kt * 32 + (lane >> 4) * 8 + j;
    int n = nt * 16 + (lane & 15);                     // 0..1023
    float v;
    if (k < HID) v = (n < HID) ? Uz[k * HID + n] : Ur[k * HID + (n - HID)];
    else {
        int kk = k - HID;                              // 0..127
        v = (n < HID) ? Wz[kk * HID + n] : Wr[kk * HID + (n - HID)];
    }
    out[idx] = (_Float16)v;
}

__global__ __launch_bounds__(256) void pack_h(
    const float* __restrict__ Uh, const float* __restrict__ Wh,
    _Float16* __restrict__ out)
{
    int idx = blockIdx.x * 256 + threadIdx.x;          // < 20*32*64*8 = 327680
    int j = idx & 7, lane = (idx >> 3) & 63, nt = (idx >> 9) & 31, kt = idx >> 14;
    int k = kt * 32 + (lane >> 4) * 8 + j;
    int n = nt * 16 + (lane & 15);                     // 0..511
    float v = (k < HID) ? Uh[k * HID + n] : Wh[(k - HID) * HID + n];
    out[idx] = (_Float16)v;
}

// ---------------------------------------------------------------------------
// Persistent GRU: one block = 16 batch rows, full 256-step recurrence.
// 1024 threads = 16 waves.  Phase A: [16,1024] = (z|r), K=640 (h|x).
// Phase B: [16,512] = hh, K=640 (v|x).  2 barriers/step.
// A-frag: lane l holds A[m = l&15][k = kt*32 + (l>>4)*8 + j]
// C-frag: col = l&15, row = (l>>4)*4 + reg   [verified layout]
// ---------------------------------------------------------------------------
__global__ __launch_bounds__(1024) void gru_persistent(
    const float* __restrict__ x, const _Float16* __restrict__ Wzr,
    const _Float16* __restrict__ Whp, const float* __restrict__ bz,
    const float* __restrict__ br, const float* __restrict__ bh,
    float* __restrict__ hout)
{
    __shared__ _Float16 APACK[16][64][8];      // h as A-frags (k 0..511), 16 KB
    __shared__ _Float16 XPACK[2][4][64][8];    // x_t A-frags (k 512..639), dbuf, 8 KB
    __shared__ _Float16 VPACK[16][64][8];      // v = r*h as A-frags, 16 KB
    __shared__ float    ZBUF[16][512];         // z gate, 32 KB
    __shared__ float    H32[16][512];          // fp32 master h, 32 KB

    const int tid = threadIdx.x;
    const int w = tid >> 6;          // wave 0..15
    const int l = tid & 63;
    const int b0 = blockIdx.x * 16;
    const int m  = l & 15;           // A-row / C-col index
    const int kq = l >> 4;           // 0..3
    const int crow0 = kq * 4;        // C rows base

    // ---- init: h = 0 ----
    for (int i = tid; i < 16 * 64 * 8; i += 1024) ((_Float16*)APACK)[i] = (_Float16)0.f;
    for (int i = tid; i < 16 * 512;   i += 1024) ((float*)H32)[i] = 0.f;
    // x frags for t=0 (waves 0..3 each own one kt)
    if (w < 4) {
        const float* xr = &x[((size_t)(b0 + m) * SEQN + 0) * INDIM + w * 32 + kq * 8];
        float4 x0 = *(const float4*)xr, x1 = *(const float4*)(xr + 4);
        _Float16* d = &XPACK[0][w][l][0];
        d[0] = (_Float16)x0.x; d[1] = (_Float16)x0.y; d[2] = (_Float16)x0.z; d[3] = (_Float16)x0.w;
        d[4] = (_Float16)x1.x; d[5] = (_Float16)x1.y; d[6] = (_Float16)x1.z; d[7] = (_Float16)x1.w;
    }

    // hoist biases: phase A tiles (4 per wave), phase B tiles (2 per wave)
    float biasA[4], biasB[2];
    #pragma unroll
    for (int i = 0; i < 4; ++i) {
        int col = (w * 4 + i) * 16 + m;              // 0..1023 combined
        biasA[i] = (col < HID) ? bz[col] : br[col - HID];
    }
    #pragma unroll
    for (int i = 0; i < 2; ++i) biasB[i] = bh[(w * 2 + i) * 16 + m];

    __syncthreads();

    for (int t = 0; t < SEQN; ++t) {
        // ================= phase A: z | r  =================
        f32x4 acc[4] = {{0,0,0,0},{0,0,0,0},{0,0,0,0},{0,0,0,0}};
        {
            const half8* bp = (const half8*)&Wzr[((size_t)(0 * 64 + w * 4) * 64 + l) * 8];
            #pragma unroll 2
            for (int kt = 0; kt < 16; ++kt) {
                half8 af = *(const half8*)&APACK[kt][l][0];
                #pragma unroll
                for (int i = 0; i < 4; ++i)
                    acc[i] = __builtin_amdgcn_mfma_f32_16x16x32_f16(af, bp[(size_t)kt*64*64 + i*64], acc[i], 0, 0, 0);
            }
            #pragma unroll
            for (int kt = 16; kt < 20; ++kt) {
                half8 af = *(const half8*)&XPACK[t & 1][kt - 16][l][0];
                #pragma unroll
                for (int i = 0; i < 4; ++i)
                    acc[i] = __builtin_amdgcn_mfma_f32_16x16x32_f16(af, bp[(size_t)kt*64*64 + i*64], acc[i], 0, 0, 0);
            }
        }
        // epilogue: waves 0-7 -> z, waves 8-15 -> r -> v = r*h
        if (w < 8) {
            #pragma unroll
            for (int i = 0; i < 4; ++i) {
                int col = (w * 4 + i) * 16 + m;
                #pragma unroll
                for (int r = 0; r < 4; ++r) {
                    float pre = acc[i][r] + biasA[i];
                    ZBUF[crow0 + r][col] = fminf(fmaxf(0.2f * pre + 0.5f, 0.f), 1.f);
                }
            }
        } else {
            #pragma unroll
            for (int i = 0; i < 4; ++i) {
                int c2 = ((w - 8) * 4 + i) * 16 + m;   // 0..511
                #pragma unroll
                for (int r = 0; r < 4; ++r) {
                    float pre = acc[i][r] + biasA[i];
                    float g = fminf(fmaxf(0.2f * pre + 0.5f, 0.f), 1.f);
                    float vv = g * H32[crow0 + r][c2];
                    VPACK[c2 >> 5][(crow0 + r) + (((c2 >> 3) & 3) << 4)][c2 & 7] = (_Float16)vv;
                }
            }
        }
        __syncthreads();

        // ================= phase B: hh, h update =================
        f32x4 acc2[2] = {{0,0,0,0},{0,0,0,0}};
        {
            const half8* bp = (const half8*)&Whp[((size_t)(0 * 32 + w * 2) * 64 + l) * 8];
            #pragma unroll 2
            for (int kt = 0; kt < 16; ++kt) {
                half8 af = *(const half8*)&VPACK[kt][l][0];
                acc2[0] = __builtin_amdgcn_mfma_f32_16x16x32_f16(af, bp[(size_t)kt*32*64 + 0],  acc2[0], 0, 0, 0);
                acc2[1] = __builtin_amdgcn_mfma_f32_16x16x32_f16(af, bp[(size_t)kt*32*64 + 64], acc2[1], 0, 0, 0);
            }
            #pragma unroll
            for (int kt = 16; kt < 20; ++kt) {
                half8 af = *(const half8*)&XPACK[t & 1][kt - 16][l][0];
                acc2[0] = __builtin_amdgcn_mfma_f32_16x16x32_f16(af, bp[(size_t)kt*32*64 + 0],  acc2[0], 0, 0, 0);
                acc2[1] = __builtin_amdgcn_mfma_f32_16x16x32_f16(af, bp[(size_t)kt*32*64 + 64], acc2[1], 0, 0, 0);
            }
        }
        // epilogue: each lane owns its (row,col) -> safe without extra barrier
        #pragma unroll
        for (int i = 0; i < 2; ++i) {
            int col = (w * 2 + i) * 16 + m;
            #pragma unroll
            for (int r = 0; r < 4; ++r) {
                int row = crow0 + r;
                float pre = acc2[i][r] + biasB[i];
                float e  = __expf(2.f * pre);
                float hh = 1.f - 2.f / (e + 1.f);      // tanh(pre)
                float zz = ZBUF[row][col];
                float ho = H32[row][col];
                float hn = zz * ho + (1.f - zz) * hh;
                H32[row][col] = hn;
                APACK[col >> 5][row + (((col >> 3) & 3) << 4)][col & 7] = (_Float16)hn;
            }
        }
        // x prefetch for t+1 (waves 0..3), into the other XPACK buffer
        if (w < 4 && t + 1 < SEQN) {
            const float* xr = &x[((size_t)(b0 + m) * SEQN + (t + 1)) * INDIM + w * 32 + kq * 8];
            float4 x0 = *(const float4*)xr, x1 = *(const float4*)(xr + 4);
            _Float16* d = &XPACK[(t + 1) & 1][w][l][0];
            d[0] = (_Float16)x0.x; d[1] = (_Float16)x0.y; d[2] = (_Float16)x0.z; d[3] = (_Float16)x0.w;
            d[4] = (_Float16)x1.x; d[5] = (_Float16)x1.y; d[6] = (_Float16)x1.z; d[7] = (_Float16)x1.w;
        }
        __syncthreads();
    }

    // write final h (fp32) for the head
    for (int i = tid; i < 16 * 512; i += 1024) {
        int row = i >> 9, col = i & 511;
        hout[(size_t)(b0 + row) * HID + col] = H32[row][col];
    }
}

// ---------------------------------------------------------------------------
// Head kernels (unchanged from round 1 — fp32, proven correct)
// ---------------------------------------------------------------------------
__global__ __launch_bounds__(256) void maxout_k(
    const float* __restrict__ h, const float* __restrict__ moW,
    const float* __restrict__ mob, float* __restrict__ m)
{
    const int ot = blockIdx.x, bt = blockIdx.y;
    __shared__ float sA[32][33];
    __shared__ float sB[4][32][33];
    const int tid = threadIdx.x;
    const int tx = tid & 15, ty = tid >> 4;
    const int b0 = bt * 32, o0 = ot * 32;
    const int lr = tid >> 3, lk4 = (tid & 7) << 2;

    float acc[4][2][2];
    #pragma unroll
    for (int p = 0; p < 4; ++p)
        acc[p][0][0] = acc[p][0][1] = acc[p][1][0] = acc[p][1][1] = 0.f;

    for (int kt = 0; kt < 16; ++kt) {
        const int k0 = kt * 32;
        float4 a = *reinterpret_cast<const float4*>(&h[(b0 + lr) * HID + k0 + lk4]);
        float4 wv[4];
        #pragma unroll
        for (int p = 0; p < 4; ++p)
            wv[p] = *reinterpret_cast<const float4*>(&moW[((size_t)p * HID + k0 + lr) * MID + o0 + lk4]);
        __syncthreads();
        sA[lk4+0][lr] = a.x; sA[lk4+1][lr] = a.y; sA[lk4+2][lr] = a.z; sA[lk4+3][lr] = a.w;
        #pragma unroll
        for (int p = 0; p < 4; ++p) {
            sB[p][lr][lk4+0] = wv[p].x; sB[p][lr][lk4+1] = wv[p].y;
            sB[p][lr][lk4+2] = wv[p].z; sB[p][lr][lk4+3] = wv[p].w;
        }
        __syncthreads();
        #pragma unroll
        for (int kk = 0; kk < 32; ++kk) {
            float a0 = sA[kk][ty*2], a1 = sA[kk][ty*2+1];
            #pragma unroll
            for (int p = 0; p < 4; ++p) {
                float w0 = sB[p][kk][tx*2], w1 = sB[p][kk][tx*2+1];
                acc[p][0][0] += a0*w0; acc[p][0][1] += a0*w1;
                acc[p][1][0] += a1*w0; acc[p][1][1] += a1*w1;
            }
        }
    }

    #pragma unroll
    for (int q = 0; q < 2; ++q)
        #pragma unroll
        for (int c = 0; c < 2; ++c) {
            const int row = b0 + ty*2 + q, col = o0 + tx*2 + c;
            float best = -1e30f;
            #pragma unroll
            for (int p = 0; p < 4; ++p)
                best = fmaxf(best, acc[p][q][c] + mob[p * MID + col]);
            m[row * MID + col] = best;
        }
}

__global__ __launch_bounds__(256) void dense1_k(
    const float* __restrict__ m, const float* __restrict__ W,
    const float* __restrict__ b, float* __restrict__ a1)
{
    const int jt = blockIdx.x, bt = blockIdx.y;
    __shared__ float sA[32][33];
    __shared__ float sB[32][33];
    const int tid = threadIdx.x;
    const int tx = tid & 15, ty = tid >> 4;
    const int b0 = bt * 32, j0 = jt * 32;
    const int lr = tid >> 3, lk4 = (tid & 7) << 2;

    float acc[2][2] = {{0.f,0.f},{0.f,0.f}};

    for (int kt = 0; kt < 8; ++kt) {
        const int k0 = kt * 32;
        float4 a  = *reinterpret_cast<const float4*>(&m[(b0 + lr) * MID + k0 + lk4]);
        float4 bv = *reinterpret_cast<const float4*>(&W[(k0 + lr) * MID + j0 + lk4]);
        __syncthreads();
        sA[lk4+0][lr] = a.x; sA[lk4+1][lr] = a.y; sA[lk4+2][lr] = a.z; sA[lk4+3][lr] = a.w;
        sB[lr][lk4+0] = bv.x; sB[lr][lk4+1] = bv.y; sB[lr][lk4+2] = bv.z; sB[lr][lk4+3] = bv.w;
        __syncthreads();
        #pragma unroll
        for (int kk = 0; kk < 32; ++kk) {
            float a0 = sA[kk][ty*2], a1v = sA[kk][ty*2+1];
            float w0 = sB[kk][tx*2], w1 = sB[kk][tx*2+1];
            acc[0][0] += a0*w0; acc[0][1] += a0*w1;
            acc[1][0] += a1v*w0; acc[1][1] += a1v*w1;
        }
    }

    #pragma unroll
    for (int q = 0; q < 2; ++q)
        #pragma unroll
        for (int c = 0; c < 2; ++c) {
            const int row = b0 + ty*2 + q, col = j0 + tx*2 + c;
            a1[row * MID + col] = acc[q][c] + b[col];
        }
}

__global__ __launch_bounds__(256) void highway_k(
    const float* __restrict__ a1,
    const float* __restrict__ hwW, const float* __restrict__ hwb,
    const float* __restrict__ hwWc, const float* __restrict__ hwbc,
    float* __restrict__ h2)
{
    const int jt = blockIdx.x, bt = blockIdx.y;
    __shared__ float sA[32][33];
    __shared__ float sBh[32][33];
    __shared__ float sBc[32][33];
    const int tid = threadIdx.x;
    const int tx = tid & 15, ty = tid >> 4;
    const int b0 = bt * 32, j0 = jt * 32;
    const int lr = tid >> 3, lk4 = (tid & 7) << 2;

    float acch[2][2] = {{0.f,0.f},{0.f,0.f}};
    float accc[2][2] = {{0.f,0.f},{0.f,0.f}};

    for (int kt = 0; kt < 8; ++kt) {
        const int k0 = kt * 32;
        float4 a   = *reinterpret_cast<const float4*>(&a1[(b0 + lr) * MID + k0 + lk4]);
        float4 bh4 = *reinterpret_cast<const float4*>(&hwW[(k0 + lr) * MID + j0 + lk4]);
        float4 bc4 = *reinterpret_cast<const float4*>(&hwWc[(k0 + lr) * MID + j0 + lk4]);
        __syncthreads();
        sA[lk4+0][lr] = a.x; sA[lk4+1][lr] = a.y; sA[lk4+2][lr] = a.z; sA[lk4+3][lr] = a.w;
        sBh[lr][lk4+0] = bh4.x; sBh[lr][lk4+1] = bh4.y; sBh[lr][lk4+2] = bh4.z; sBh[lr][lk4+3] = bh4.w;
        sBc[lr][lk4+0] = bc4.x; sBc[lr][lk4+1] = bc4.y; sBc[lr][lk4+2] = bc4.z; sBc[lr][lk4+3] = bc4.w;
        __syncthreads();
        #pragma unroll
        for (int kk = 0; kk < 32; ++kk) {
            float a0 = sA[kk][ty*2], a1v = sA[kk][ty*2+1];
            float h0 = sBh[kk][tx*2], h1 = sBh[kk][tx*2+1];
            float c0 = sBc[kk][tx*2], c1 = sBc[kk][tx*2+1];
            acch[0][0] += a0*h0; acch[0][1] += a0*h1;
            acch[1][0] += a1v*h0; acch[1][1] += a1v*h1;
            accc[0][0] += a0*c0; accc[0][1] += a0*c1;
            accc[1][0] += a1v*c0; accc[1][1] += a1v*c1;
        }
    }

    #pragma unroll
    for (int q = 0; q < 2; ++q)
        #pragma unroll
        for (int c = 0; c < 2; ++c) {
            const int row = b0 + ty*2 + q, col = j0 + tx*2 + c;
            float tt = 1.f / (1.f + expf(-(accc[q][c] + hwbc[col])));
            float hp = fmaxf(acch[q][c] + hwb[col], 0.f);
            float av = a1[row * MID + col];
            h2[row * MID + col] = tt * hp + (1.f - tt) * av;
        }
}

__global__ __launch_bounds__(256) void d2_softmax(
    const float* __restrict__ h2, const float* __restrict__ W,
    const float* __restrict__ b, float* __restrict__ out)
{
    const int b0 = blockIdx.x * 16;
    const int r = threadIdx.x >> 4, c = threadIdx.x & 15;
    const int row = b0 + r;

    float acc = b[c];
    for (int i = 0; i < MID; ++i)
        acc += h2[row * MID + i] * W[i * NCLS + c];

    float mx = acc;
    #pragma unroll
    for (int off = 8; off; off >>= 1)
        mx = fmaxf(mx, __shfl_xor(mx, off, 16));
    float e = expf(acc - mx);
    float s = e;
    #pragma unroll
    for (int off = 8; off; off >>= 1)
        s += __shfl_xor(s, off, 16);
    out[row * NCLS + c] = e / s;
}

// ---------------------------------------------------------------------------
extern "C" void kernel_launch(void* const* d_in, const int* in_sizes, int n_in,
                              void* d_out, int out_size, void* d_ws, size_t ws_size,
                              hipStream_t stream) {
    (void)in_sizes; (void)n_in; (void)out_size; (void)ws_size;

    const float* x    = (const float*)d_in[0];
    const float* Wz   = (const float*)d_in[1];
    const float* Wr   = (const float*)d_in[2];
    const float* Wh   = (const float*)d_in[3];
    const float* Uz   = (const float*)d_in[4];
    const float* Ur   = (const float*)d_in[5];
    const float* Uh   = (const float*)d_in[6];
    const float* bz   = (const float*)d_in[7];
    const float* br   = (const float*)d_in[8];
    const float* bh   = (const float*)d_in[9];
    const float* moW  = (const float*)d_in[10];
    const float* mob  = (const float*)d_in[11];
    const float* d1W  = (const float*)d_in[12];
    const float* d1b  = (const float*)d_in[13];
    const float* hwW  = (const float*)d_in[14];
    const float* hwb  = (const float*)d_in[15];
    const float* hwWc = (const float*)d_in[16];
    const float* hwbc = (const float*)d_in[17];
    const float* d2W  = (const float*)d_in[18];
    const float* d2b  = (const float*)d_in[19];
    float* out = (float*)d_out;

    char* ws = (char*)d_ws;
    _Float16* wzr  = (_Float16*)(ws);                       // 1,310,720 B
    _Float16* whp  = (_Float16*)(ws + 1310720);             //   655,360 B
    float*    hbuf = (float*)(ws + 1966080);                //   524,288 B
    float*    mxb  = (float*)(ws + 2490368);                //   262,144 B
    float*    a1b  = (float*)(ws + 2752512);                //   262,144 B
    float*    h2b  = (float*)(ws + 3014656);                //   262,144 B

    pack_zr<<<2560, 256, 0, stream>>>(Uz, Ur, Wz, Wr, wzr);
    pack_h<<<1280, 256, 0, stream>>>(Uh, Wh, whp);

    gru_persistent<<<16, 1024, 0, stream>>>(x, wzr, whp, bz, br, bh, hbuf);

    dim3 blk(256);
    maxout_k<<<dim3(8, 8), blk, 0, stream>>>(hbuf, moW, mob, mxb);
    dense1_k<<<dim3(8, 8), blk, 0, stream>>>(mxb, d1W, d1b, a1b);
    highway_k<<<dim3(8, 8), blk, 0, stream>>>(a1b, hwW, hwb, hwWc, hwbc, h2b);
    d2_softmax<<<16, blk, 0, stream>>>(h2b, d2W, d2b, out);
}

// Round 3
// 3373.176 us; speedup vs baseline: 3.4626x; 1.1752x over previous
//
#include <hip/hip_runtime.h>
#include <hip/hip_bf16.h>
#include <math.h>

#define BATCH 256
#define SEQN  256
#define INDIM 128
#define HID   512
#define MID   256
#define NCLS  16

#define NG 8     // batch groups
#define RG 32    // rows per group
#define NS 16    // column slices (partner blocks per group)
#define SC 32    // cols per slice (of each of z, r, hh)

typedef _Float16 half8 __attribute__((ext_vector_type(8)));
typedef float    f32x4 __attribute__((ext_vector_type(4)));

// ---------------------------------------------------------------------------
// Weight packs into per-slice B-frag layout (16x16x32 f16 MFMA):
//   B-frag: lane l holds B[k = kt*32 + (l>>4)*8 + j][n = l&15]
// GWA[s][nt4][kt][l][j]  nt4 0,1 = z-ntiles, 2,3 = r-ntiles; K=640 (U | W)
// GWB[s][nt2][kt][l][j]  hh ntiles
// ---------------------------------------------------------------------------
__global__ __launch_bounds__(256) void pack_wA(
    const float* __restrict__ Uz, const float* __restrict__ Ur,
    const float* __restrict__ Wz, const float* __restrict__ Wr,
    _Float16* __restrict__ out)
{
    int idx = blockIdx.x * 256 + threadIdx.x;        // < 16*4*20*512 = 655360
    int j = idx & 7, l = (idx >> 3) & 63;
    int fr = idx >> 9;                               // s*80 + nt4*20 + kt
    int kt = fr % 20; int r2 = fr / 20;
    int nt4 = r2 & 3; int s = r2 >> 2;
    int k = kt * 32 + (l >> 4) * 8 + j;
    int col = s * SC + (nt4 & 1) * 16 + (l & 15);    // 0..511
    const float* U = (nt4 < 2) ? Uz : Ur;
    const float* W = (nt4 < 2) ? Wz : Wr;
    float v = (k < HID) ? U[k * HID + col] : W[(k - HID) * HID + col];
    out[idx] = (_Float16)v;
}

__global__ __launch_bounds__(256) void pack_wB(
    const float* __restrict__ Uh, const float* __restrict__ Wh,
    _Float16* __restrict__ out)
{
    int idx = blockIdx.x * 256 + threadIdx.x;        // < 16*2*20*512 = 327680
    int j = idx & 7, l = (idx >> 3) & 63;
    int fr = idx >> 9;                               // s*40 + nt2*20 + kt
    int kt = fr % 20; int r2 = fr / 20;
    int nt2 = r2 & 1; int s = r2 >> 1;
    int k = kt * 32 + (l >> 4) * 8 + j;
    int col = s * SC + nt2 * 16 + (l & 15);
    float v = (k < HID) ? Uh[k * HID + col] : Wh[(k - HID) * HID + col];
    out[idx] = (_Float16)v;
}

// ---------------------------------------------------------------------------
// Weight-stationary GRU. 128 blocks = 8 groups x 16 slices, bid = s*8 + g.
// Block (g,s): rows [g*32, g*32+32), owns cols [s*32, s*32+32) of z, r, hh.
// Weights LDS-resident (120 KB). Per step: 2 device-scope partner barriers.
// A/H/V-frag: lane l holds A[m=l&15][k = kt*32 + (l>>4)*8 + j]
// C-frag: col = l&15, row = (l>>4)*4 + reg
// ---------------------------------------------------------------------------
__global__ __launch_bounds__(512) void gru_sync(
    const float* __restrict__ x, const _Float16* __restrict__ GWA,
    const _Float16* __restrict__ GWB,
    const float* __restrict__ bz, const float* __restrict__ br,
    const float* __restrict__ bh,
    _Float16* __restrict__ HF, _Float16* __restrict__ VF,
    unsigned int* __restrict__ cnt, float* __restrict__ hout)
{
    __shared__ _Float16 WA[4][20][64][8];   // 80 KB  z|r weight slice
    __shared__ _Float16 WB[2][20][64][8];   // 40 KB  hh weight slice
    __shared__ float    HO[RG][SC];         // 4 KB   f32 master h (own cols)

    const int tid = threadIdx.x;
    const int w = tid >> 6, l = tid & 63;
    const int bid = blockIdx.x;
    const int g = bid & 7, s = bid >> 3;
    const int m = l & 15;
    const int crow0 = (l >> 4) * 4;

    const int mt  = w & 1;    // m-tile (rows mt*16..+16 of the 32)
    const int nt4 = w >> 1;   // phase A: 0,1 = z-ntiles; 2,3 = r-ntiles
    const int nt2 = w >> 1;   // phase B (w<4 only)

    // ---- stage weight slices into LDS ----
    {
        const float4* srcA = (const float4*)&GWA[(size_t)s * (4 * 20 * 512)];
        float4* dstA = (float4*)&WA[0][0][0][0];
        for (int i = tid; i < 4 * 20 * 512 / 8; i += 512) dstA[i] = srcA[i];
        const float4* srcB = (const float4*)&GWB[(size_t)s * (2 * 20 * 512)];
        float4* dstB = (float4*)&WB[0][0][0][0];
        for (int i = tid; i < 2 * 20 * 512 / 8; i += 512) dstB[i] = srcB[i];
    }
    for (int i = tid; i < RG * SC; i += 512) ((float*)HO)[i] = 0.f;

    // ---- biases (per-wave tile is fixed) ----
    float biasA;
    {
        int col = s * SC + (nt4 & 1) * 16 + m;
        biasA = (nt4 < 2) ? bz[col] : br[col];
    }
    float biasB = 0.f;
    if (w < 4) biasB = bh[s * SC + nt2 * 16 + m];

    unsigned int* flag = &cnt[g * 32];     // 128B-padded per-group counter
    __syncthreads();

    float zreg[4];   // z values (phase A tile == phase B tile for waves 0..3)

    for (int t = 0; t < SEQN; ++t) {
        // ---- x A-frags for this wave's m-tile (read f32 direct, cvt f16) ----
        half8 xf[4];
        {
            const float* xp = &x[(((size_t)(g * RG + mt * 16 + m)) * SEQN + t) * INDIM + (l >> 4) * 8];
            #pragma unroll
            for (int kf = 0; kf < 4; ++kf) {
                float4 a0 = *(const float4*)(xp + kf * 32);
                float4 a1 = *(const float4*)(xp + kf * 32 + 4);
                half8 hx;
                hx[0] = (_Float16)a0.x; hx[1] = (_Float16)a0.y;
                hx[2] = (_Float16)a0.z; hx[3] = (_Float16)a0.w;
                hx[4] = (_Float16)a1.x; hx[5] = (_Float16)a1.y;
                hx[6] = (_Float16)a1.z; hx[7] = (_Float16)a1.w;
                xf[kf] = hx;
            }
        }

        // ================= phase A: z_s | r_s =================
        {
            f32x4 acc = {0.f, 0.f, 0.f, 0.f};
            const _Float16* hf = &HF[(size_t)(g * 2 + mt) * 16 * 512];
            #pragma unroll 4
            for (int kt = 0; kt < 16; ++kt) {
                half8 af = *(const half8*)&hf[kt * 512 + l * 8];
                half8 bf = *(const half8*)&WA[nt4][kt][l][0];
                acc = __builtin_amdgcn_mfma_f32_16x16x32_f16(af, bf, acc, 0, 0, 0);
            }
            #pragma unroll
            for (int kf = 0; kf < 4; ++kf) {
                half8 bf = *(const half8*)&WA[nt4][16 + kf][l][0];
                acc = __builtin_amdgcn_mfma_f32_16x16x32_f16(xf[kf], bf, acc, 0, 0, 0);
            }
            if (nt4 < 2) {
                #pragma unroll
                for (int ri = 0; ri < 4; ++ri) {
                    float pre = acc[ri] + biasA;
                    zreg[ri] = fminf(fmaxf(0.2f * pre + 0.5f, 0.f), 1.f);
                }
            } else {
                #pragma unroll
                for (int ri = 0; ri < 4; ++ri) {
                    float pre = acc[ri] + biasA;
                    float gr = fminf(fmaxf(0.2f * pre + 0.5f, 0.f), 1.f);
                    int rloc = mt * 16 + crow0 + ri;
                    int cs = (nt4 & 1) * 16 + m;
                    float vv = gr * HO[rloc][cs];
                    VF[(((size_t)(g * 2 + mt) * 16 + s) * 64 +
                        ((crow0 + ri) + 16 * (cs >> 3))) * 8 + (cs & 7)] = (_Float16)vv;
                }
            }
        }

        // ---- barrier 1: v published ----
        __syncthreads();
        if (tid == 0) {
            __hip_atomic_fetch_add(flag, 1u, __ATOMIC_RELEASE, __HIP_MEMORY_SCOPE_AGENT);
            unsigned int tgt = (unsigned int)(2 * t + 1) * NS;
            while (__hip_atomic_load(flag, __ATOMIC_RELAXED, __HIP_MEMORY_SCOPE_AGENT) < tgt)
                __builtin_amdgcn_s_sleep(1);
            (void)__hip_atomic_load(flag, __ATOMIC_ACQUIRE, __HIP_MEMORY_SCOPE_AGENT);
        }
        __syncthreads();

        // ================= phase B: hh_s, h update =================
        if (w < 4) {
            f32x4 acc2 = {0.f, 0.f, 0.f, 0.f};
            const _Float16* vf = &VF[(size_t)(g * 2 + mt) * 16 * 512];
            #pragma unroll 4
            for (int kt = 0; kt < 16; ++kt) {
                half8 af = *(const half8*)&vf[kt * 512 + l * 8];
                half8 bf = *(const half8*)&WB[nt2][kt][l][0];
                acc2 = __builtin_amdgcn_mfma_f32_16x16x32_f16(af, bf, acc2, 0, 0, 0);
            }
            #pragma unroll
            for (int kf = 0; kf < 4; ++kf) {
                half8 bf = *(const half8*)&WB[nt2][16 + kf][l][0];
                acc2 = __builtin_amdgcn_mfma_f32_16x16x32_f16(xf[kf], bf, acc2, 0, 0, 0);
            }
            #pragma unroll
            for (int ri = 0; ri < 4; ++ri) {
                float pre = acc2[ri] + biasB;
                float e  = __expf(2.f * pre);
                float hh = 1.f - 2.f / (e + 1.f);          // tanh(pre)
                int rloc = mt * 16 + crow0 + ri;
                int cs = nt2 * 16 + m;
                float zz = zreg[ri];
                float ho = HO[rloc][cs];
                float hn = zz * ho + (1.f - zz) * hh;
                HO[rloc][cs] = hn;
                HF[(((size_t)(g * 2 + mt) * 16 + s) * 64 +
                    ((crow0 + ri) + 16 * (cs >> 3))) * 8 + (cs & 7)] = (_Float16)hn;
            }
        }

        // ---- barrier 2: h' published ----
        __syncthreads();
        if (tid == 0) {
            __hip_atomic_fetch_add(flag, 1u, __ATOMIC_RELEASE, __HIP_MEMORY_SCOPE_AGENT);
            unsigned int tgt = (unsigned int)(2 * t + 2) * NS;
            while (__hip_atomic_load(flag, __ATOMIC_RELAXED, __HIP_MEMORY_SCOPE_AGENT) < tgt)
                __builtin_amdgcn_s_sleep(1);
            (void)__hip_atomic_load(flag, __ATOMIC_ACQUIRE, __HIP_MEMORY_SCOPE_AGENT);
        }
        __syncthreads();
    }

    // ---- write final h (own slice, f32) ----
    for (int i = tid; i < RG * SC; i += 512) {
        int r = i >> 5, c = i & 31;
        hout[(size_t)(g * RG + r) * HID + s * SC + c] = HO[r][c];
    }
}

// ---------------------------------------------------------------------------
// Head kernels (unchanged — fp32, proven correct)
// ---------------------------------------------------------------------------
__global__ __launch_bounds__(256) void maxout_k(
    const float* __restrict__ h, const float* __restrict__ moW,
    const float* __restrict__ mob, float* __restrict__ m)
{
    const int ot = blockIdx.x, bt = blockIdx.y;
    __shared__ float sA[32][33];
    __shared__ float sB[4][32][33];
    const int tid = threadIdx.x;
    const int tx = tid & 15, ty = tid >> 4;
    const int b0 = bt * 32, o0 = ot * 32;
    const int lr = tid >> 3, lk4 = (tid & 7) << 2;

    float acc[4][2][2];
    #pragma unroll
    for (int p = 0; p < 4; ++p)
        acc[p][0][0] = acc[p][0][1] = acc[p][1][0] = acc[p][1][1] = 0.f;

    for (int kt = 0; kt < 16; ++kt) {
        const int k0 = kt * 32;
        float4 a = *reinterpret_cast<const float4*>(&h[(b0 + lr) * HID + k0 + lk4]);
        float4 wv[4];
        #pragma unroll
        for (int p = 0; p < 4; ++p)
            wv[p] = *reinterpret_cast<const float4*>(&moW[((size_t)p * HID + k0 + lr) * MID + o0 + lk4]);
        __syncthreads();
        sA[lk4+0][lr] = a.x; sA[lk4+1][lr] = a.y; sA[lk4+2][lr] = a.z; sA[lk4+3][lr] = a.w;
        #pragma unroll
        for (int p = 0; p < 4; ++p) {
            sB[p][lr][lk4+0] = wv[p].x; sB[p][lr][lk4+1] = wv[p].y;
            sB[p][lr][lk4+2] = wv[p].z; sB[p][lr][lk4+3] = wv[p].w;
        }
        __syncthreads();
        #pragma unroll
        for (int kk = 0; kk < 32; ++kk) {
            float a0 = sA[kk][ty*2], a1 = sA[kk][ty*2+1];
            #pragma unroll
            for (int p = 0; p < 4; ++p) {
                float w0 = sB[p][kk][tx*2], w1 = sB[p][kk][tx*2+1];
                acc[p][0][0] += a0*w0; acc[p][0][1] += a0*w1;
                acc[p][1][0] += a1*w0; acc[p][1][1] += a1*w1;
            }
        }
    }

    #pragma unroll
    for (int q = 0; q < 2; ++q)
        #pragma unroll
        for (int c = 0; c < 2; ++c) {
            const int row = b0 + ty*2 + q, col = o0 + tx*2 + c;
            float best = -1e30f;
            #pragma unroll
            for (int p = 0; p < 4; ++p)
                best = fmaxf(best, acc[p][q][c] + mob[p * MID + col]);
            m[row * MID + col] = best;
        }
}

__global__ __launch_bounds__(256) void dense1_k(
    const float* __restrict__ m, const float* __restrict__ W,
    const float* __restrict__ b, float* __restrict__ a1)
{
    const int jt = blockIdx.x, bt = blockIdx.y;
    __shared__ float sA[32][33];
    __shared__ float sB[32][33];
    const int tid = threadIdx.x;
    const int tx = tid & 15, ty = tid >> 4;
    const int b0 = bt * 32, j0 = jt * 32;
    const int lr = tid >> 3, lk4 = (tid & 7) << 2;

    float acc[2][2] = {{0.f,0.f},{0.f,0.f}};

    for (int kt = 0; kt < 8; ++kt) {
        const int k0 = kt * 32;
        float4 a  = *reinterpret_cast<const float4*>(&m[(b0 + lr) * MID + k0 + lk4]);
        float4 bv = *reinterpret_cast<const float4*>(&W[(k0 + lr) * MID + j0 + lk4]);
        __syncthreads();
        sA[lk4+0][lr] = a.x; sA[lk4+1][lr] = a.y; sA[lk4+2][lr] = a.z; sA[lk4+3][lr] = a.w;
        sB[lr][lk4+0] = bv.x; sB[lr][lk4+1] = bv.y; sB[lr][lk4+2] = bv.z; sB[lr][lk4+3] = bv.w;
        __syncthreads();
        #pragma unroll
        for (int kk = 0; kk < 32; ++kk) {
            float a0 = sA[kk][ty*2], a1v = sA[kk][ty*2+1];
            float w0 = sB[kk][tx*2], w1 = sB[kk][tx*2+1];
            acc[0][0] += a0*w0; acc[0][1] += a0*w1;
            acc[1][0] += a1v*w0; acc[1][1] += a1v*w1;
        }
    }

    #pragma unroll
    for (int q = 0; q < 2; ++q)
        #pragma unroll
        for (int c = 0; c < 2; ++c) {
            const int row = b0 + ty*2 + q, col = j0 + tx*2 + c;
            a1[row * MID + col] = acc[q][c] + b[col];
        }
}

__global__ __launch_bounds__(256) void highway_k(
    const float* __restrict__ a1,
    const float* __restrict__ hwW, const float* __restrict__ hwb,
    const float* __restrict__ hwWc, const float* __restrict__ hwbc,
    float* __restrict__ h2)
{
    const int jt = blockIdx.x, bt = blockIdx.y;
    __shared__ float sA[32][33];
    __shared__ float sBh[32][33];
    __shared__ float sBc[32][33];
    const int tid = threadIdx.x;
    const int tx = tid & 15, ty = tid >> 4;
    const int b0 = bt * 32, j0 = jt * 32;
    const int lr = tid >> 3, lk4 = (tid & 7) << 2;

    float acch[2][2] = {{0.f,0.f},{0.f,0.f}};
    float accc[2][2] = {{0.f,0.f},{0.f,0.f}};

    for (int kt = 0; kt < 8; ++kt) {
        const int k0 = kt * 32;
        float4 a   = *reinterpret_cast<const float4*>(&a1[(b0 + lr) * MID + k0 + lk4]);
        float4 bh4 = *reinterpret_cast<const float4*>(&hwW[(k0 + lr) * MID + j0 + lk4]);
        float4 bc4 = *reinterpret_cast<const float4*>(&hwWc[(k0 + lr) * MID + j0 + lk4]);
        __syncthreads();
        sA[lk4+0][lr] = a.x; sA[lk4+1][lr] = a.y; sA[lk4+2][lr] = a.z; sA[lk4+3][lr] = a.w;
        sBh[lr][lk4+0] = bh4.x; sBh[lr][lk4+1] = bh4.y; sBh[lr][lk4+2] = bh4.z; sBh[lr][lk4+3] = bh4.w;
        sBc[lr][lk4+0] = bc4.x; sBc[lr][lk4+1] = bc4.y; sBc[lr][lk4+2] = bc4.z; sBc[lr][lk4+3] = bc4.w;
        __syncthreads();
        #pragma unroll
        for (int kk = 0; kk < 32; ++kk) {
            float a0 = sA[kk][ty*2], a1v = sA[kk][ty*2+1];
            float h0 = sBh[kk][tx*2], h1 = sBh[kk][tx*2+1];
            float c0 = sBc[kk][tx*2], c1 = sBc[kk][tx*2+1];
            acch[0][0] += a0*h0; acch[0][1] += a0*h1;
            acch[1][0] += a1v*h0; acch[1][1] += a1v*h1;
            accc[0][0] += a0*c0; accc[0][1] += a0*c1;
            accc[1][0] += a1v*c0; accc[1][1] += a1v*c1;
        }
    }

    #pragma unroll
    for (int q = 0; q < 2; ++q)
        #pragma unroll
        for (int c = 0; c < 2; ++c) {
            const int row = b0 + ty*2 + q, col = j0 + tx*2 + c;
            float tt = 1.f / (1.f + expf(-(accc[q][c] + hwbc[col])));
            float hp = fmaxf(acch[q][c] + hwb[col], 0.f);
            float av = a1[row * MID + col];
            h2[row * MID + col] = tt * hp + (1.f - tt) * av;
        }
}

__global__ __launch_bounds__(256) void d2_softmax(
    const float* __restrict__ h2, const float* __restrict__ W,
    const float* __restrict__ b, float* __restrict__ out)
{
    const int b0 = blockIdx.x * 16;
    const int r = threadIdx.x >> 4, c = threadIdx.x & 15;
    const int row = b0 + r;

    float acc = b[c];
    for (int i = 0; i < MID; ++i)
        acc += h2[row * MID + i] * W[i * NCLS + c];

    float mx = acc;
    #pragma unroll
    for (int off = 8; off; off >>= 1)
        mx = fmaxf(mx, __shfl_xor(mx, off, 16));
    float e = expf(acc - mx);
    float sm = e;
    #pragma unroll
    for (int off = 8; off; off >>= 1)
        sm += __shfl_xor(sm, off, 16);
    out[row * NCLS + c] = e / sm;
}

// ---------------------------------------------------------------------------
extern "C" void kernel_launch(void* const* d_in, const int* in_sizes, int n_in,
                              void* d_out, int out_size, void* d_ws, size_t ws_size,
                              hipStream_t stream) {
    (void)in_sizes; (void)n_in; (void)out_size; (void)ws_size;

    const float* x    = (const float*)d_in[0];
    const float* Wz   = (const float*)d_in[1];
    const float* Wr   = (const float*)d_in[2];
    const float* Wh   = (const float*)d_in[3];
    const float* Uz   = (const float*)d_in[4];
    const float* Ur   = (const float*)d_in[5];
    const float* Uh   = (const float*)d_in[6];
    const float* bz   = (const float*)d_in[7];
    const float* br   = (const float*)d_in[8];
    const float* bh   = (const float*)d_in[9];
    const float* moW  = (const float*)d_in[10];
    const float* mob  = (const float*)d_in[11];
    const float* d1W  = (const float*)d_in[12];
    const float* d1b  = (const float*)d_in[13];
    const float* hwW  = (const float*)d_in[14];
    const float* hwb  = (const float*)d_in[15];
    const float* hwWc = (const float*)d_in[16];
    const float* hwbc = (const float*)d_in[17];
    const float* d2W  = (const float*)d_in[18];
    const float* d2b  = (const float*)d_in[19];
    float* out = (float*)d_out;

    char* ws = (char*)d_ws;
    _Float16* GWA = (_Float16*)(ws + 0);              // 1,310,720 B
    _Float16* GWB = (_Float16*)(ws + 1310720);        //   655,360 B
    _Float16* HF  = (_Float16*)(ws + 1966080);        //   262,144 B
    _Float16* VF  = (_Float16*)(ws + 2228224);        //   262,144 B
    unsigned int* cnt = (unsigned int*)(ws + 2490368);//     1,024 B
    float*    hbuf = (float*)(ws + 2491392);          //   524,288 B
    // head temps overlap the GWA region (head runs strictly after gru_sync):
    float*    mxb = (float*)(ws + 0);                 //   262,144 B
    float*    a1b = (float*)(ws + 262144);            //   262,144 B
    float*    h2b = (float*)(ws + 524288);            //   262,144 B

    hipMemsetAsync(HF, 0, 262144, stream);
    hipMemsetAsync(cnt, 0, 1024, stream);

    pack_wA<<<2560, 256, 0, stream>>>(Uz, Ur, Wz, Wr, GWA);
    pack_wB<<<1280, 256, 0, stream>>>(Uh, Wh, GWB);

    gru_sync<<<128, 512, 0, stream>>>(x, GWA, GWB, bz, br, bh, HF, VF, cnt, hbuf);

    dim3 blk(256);
    maxout_k<<<dim3(8, 8), blk, 0, stream>>>(hbuf, moW, mob, mxb);
    dense1_k<<<dim3(8, 8), blk, 0, stream>>>(mxb, d1W, d1b, a1b);
    highway_k<<<dim3(8, 8), blk, 0, stream>>>(a1b, hwW, hwb, hwWc, hwbc, h2b);
    d2_softmax<<<16, blk, 0, stream>>>(h2b, d2W, d2b, out);
}

// Round 4
// 1777.391 us; speedup vs baseline: 6.5715x; 1.8978x over previous
//
#include <hip/hip_runtime.h>
#include <hip/hip_bf16.h>
#include <math.h>

#define BATCH 256
#define SEQN  256
#define INDIM 128
#define HID   512
#define MID   256
#define NCLS  16

#define NG 8     // batch groups
#define RG 32    // rows per group
#define NS 16    // column slices (partner blocks per group)
#define SC 32    // cols per slice (of each of z, r, hh)

typedef _Float16 half8 __attribute__((ext_vector_type(8)));
typedef float    f32x4 __attribute__((ext_vector_type(4)));

// ---- cross-XCD coherent memory ops (bypass L1+L2, operate at L3) ----------
__device__ __forceinline__ half8 cc_load16(const _Float16* p) {
    half8 r;
    asm volatile("global_load_dwordx4 %0, %1, off sc0 sc1" : "=&v"(r) : "v"(p));
    return r;
}
__device__ __forceinline__ void cc_wait() {
    asm volatile("s_waitcnt vmcnt(0)" ::: "memory");
    __builtin_amdgcn_sched_barrier(0);
}
__device__ __forceinline__ void cc_store16(_Float16* p, _Float16 v) {
    unsigned short u = __builtin_bit_cast(unsigned short, v);
    asm volatile("global_store_short %0, %1, off sc0 sc1" :: "v"(p), "v"(u) : "memory");
}

// ---------------------------------------------------------------------------
// Weight packs into per-slice B-frag layout (16x16x32 f16 MFMA):
//   B-frag: lane l holds B[k = kt*32 + (l>>4)*8 + j][n = l&15]
// GWA[s][nt4][kt][l][j]  nt4 0,1 = z-ntiles, 2,3 = r-ntiles; K=640 (U | W)
// GWB[s][nt2][kt][l][j]  hh ntiles
// ---------------------------------------------------------------------------
__global__ __launch_bounds__(256) void pack_wA(
    const float* __restrict__ Uz, const float* __restrict__ Ur,
    const float* __restrict__ Wz, const float* __restrict__ Wr,
    _Float16* __restrict__ out)
{
    int idx = blockIdx.x * 256 + threadIdx.x;        // < 16*4*20*512 = 655360
    int j = idx & 7, l = (idx >> 3) & 63;
    int fr = idx >> 9;                               // s*80 + nt4*20 + kt
    int kt = fr % 20; int r2 = fr / 20;
    int nt4 = r2 & 3; int s = r2 >> 2;
    int k = kt * 32 + (l >> 4) * 8 + j;
    int col = s * SC + (nt4 & 1) * 16 + (l & 15);    // 0..511
    const float* U = (nt4 < 2) ? Uz : Ur;
    const float* W = (nt4 < 2) ? Wz : Wr;
    float v = (k < HID) ? U[k * HID + col] : W[(k - HID) * HID + col];
    out[idx] = (_Float16)v;
}

__global__ __launch_bounds__(256) void pack_wB(
    const float* __restrict__ Uh, const float* __restrict__ Wh,
    _Float16* __restrict__ out)
{
    int idx = blockIdx.x * 256 + threadIdx.x;        // < 16*2*20*512 = 327680
    int j = idx & 7, l = (idx >> 3) & 63;
    int fr = idx >> 9;                               // s*40 + nt2*20 + kt
    int kt = fr % 20; int r2 = fr / 20;
    int nt2 = r2 & 1; int s = r2 >> 1;
    int k = kt * 32 + (l >> 4) * 8 + j;
    int col = s * SC + nt2 * 16 + (l & 15);
    float v = (k < HID) ? Uh[k * HID + col] : Wh[(k - HID) * HID + col];
    out[idx] = (_Float16)v;
}

// ---------------------------------------------------------------------------
// Weight-stationary GRU. 128 blocks = 8 groups x 16 slices, bid = s*8 + g.
// Block (g,s): rows [g*32, g*32+32), owns cols [s*32, s*32+32) of z, r, hh.
// Weights LDS-resident (120 KB). Per step: 2 agent-scope partner barriers
// with write-through (sc0 sc1) data exchange — no L2 writeback/invalidate.
// A/H/V-frag: lane l holds A[m=l&15][k = kt*32 + (l>>4)*8 + j]
// C-frag: col = l&15, row = (l>>4)*4 + reg
// ---------------------------------------------------------------------------
__global__ __launch_bounds__(512) void gru_sync(
    const float* __restrict__ x, const _Float16* __restrict__ GWA,
    const _Float16* __restrict__ GWB,
    const float* __restrict__ bz, const float* __restrict__ br,
    const float* __restrict__ bh,
    _Float16* __restrict__ HF, _Float16* __restrict__ VF,
    unsigned int* __restrict__ cnt, float* __restrict__ hout)
{
    __shared__ _Float16 WA[4][20][64][8];   // 80 KB  z|r weight slice
    __shared__ _Float16 WB[2][20][64][8];   // 40 KB  hh weight slice
    __shared__ float    HO[RG][SC];         // 4 KB   f32 master h (own cols)

    const int tid = threadIdx.x;
    const int w = tid >> 6, l = tid & 63;
    const int bid = blockIdx.x;
    const int g = bid & 7, s = bid >> 3;
    const int m = l & 15;
    const int crow0 = (l >> 4) * 4;

    const int mt  = w & 1;    // m-tile (rows mt*16..+16 of the 32)
    const int nt4 = w >> 1;   // phase A: 0,1 = z-ntiles; 2,3 = r-ntiles
    const int nt2 = w >> 1;   // phase B (w<4 only)

    // ---- stage weight slices into LDS ----
    {
        const float4* srcA = (const float4*)&GWA[(size_t)s * (4 * 20 * 512)];
        float4* dstA = (float4*)&WA[0][0][0][0];
        for (int i = tid; i < 4 * 20 * 512 / 8; i += 512) dstA[i] = srcA[i];
        const float4* srcB = (const float4*)&GWB[(size_t)s * (2 * 20 * 512)];
        float4* dstB = (float4*)&WB[0][0][0][0];
        for (int i = tid; i < 2 * 20 * 512 / 8; i += 512) dstB[i] = srcB[i];
    }
    for (int i = tid; i < RG * SC; i += 512) ((float*)HO)[i] = 0.f;

    // ---- biases (per-wave tile is fixed) ----
    float biasA;
    {
        int col = s * SC + (nt4 & 1) * 16 + m;
        biasA = (nt4 < 2) ? bz[col] : br[col];
    }
    float biasB = 0.f;
    if (w < 4) biasB = bh[s * SC + nt2 * 16 + m];

    unsigned int* flag = &cnt[g * 32];     // 128B-padded per-group counter
    __syncthreads();

    float zreg[4];   // z values (phase A tile == phase B tile for waves 0..3)

    for (int t = 0; t < SEQN; ++t) {
        // ---- issue h-exchange loads first (L3, 16 in flight) ----
        half8 hfr[16];
        {
            const _Float16* hf = &HF[(size_t)(g * 2 + mt) * 16 * 512];
            #pragma unroll
            for (int kt = 0; kt < 16; ++kt)
                hfr[kt] = cc_load16(hf + kt * 512 + l * 8);
        }

        // ---- x A-frags under the load shadow (normal cached loads) ----
        half8 xf[4];
        {
            const float* xp = &x[(((size_t)(g * RG + mt * 16 + m)) * SEQN + t) * INDIM + (l >> 4) * 8];
            #pragma unroll
            for (int kf = 0; kf < 4; ++kf) {
                float4 a0 = *(const float4*)(xp + kf * 32);
                float4 a1 = *(const float4*)(xp + kf * 32 + 4);
                half8 hx;
                hx[0] = (_Float16)a0.x; hx[1] = (_Float16)a0.y;
                hx[2] = (_Float16)a0.z; hx[3] = (_Float16)a0.w;
                hx[4] = (_Float16)a1.x; hx[5] = (_Float16)a1.y;
                hx[6] = (_Float16)a1.z; hx[7] = (_Float16)a1.w;
                xf[kf] = hx;
            }
        }
        cc_wait();

        // ================= phase A: z_s | r_s =================
        {
            f32x4 acc = {0.f, 0.f, 0.f, 0.f};
            #pragma unroll
            for (int kt = 0; kt < 16; ++kt) {
                half8 bf = *(const half8*)&WA[nt4][kt][l][0];
                acc = __builtin_amdgcn_mfma_f32_16x16x32_f16(hfr[kt], bf, acc, 0, 0, 0);
            }
            #pragma unroll
            for (int kf = 0; kf < 4; ++kf) {
                half8 bf = *(const half8*)&WA[nt4][16 + kf][l][0];
                acc = __builtin_amdgcn_mfma_f32_16x16x32_f16(xf[kf], bf, acc, 0, 0, 0);
            }
            if (nt4 < 2) {
                #pragma unroll
                for (int ri = 0; ri < 4; ++ri) {
                    float pre = acc[ri] + biasA;
                    zreg[ri] = fminf(fmaxf(0.2f * pre + 0.5f, 0.f), 1.f);
                }
            } else {
                #pragma unroll
                for (int ri = 0; ri < 4; ++ri) {
                    float pre = acc[ri] + biasA;
                    float gr = fminf(fmaxf(0.2f * pre + 0.5f, 0.f), 1.f);
                    int rloc = mt * 16 + crow0 + ri;
                    int cs = (nt4 & 1) * 16 + m;
                    float vv = gr * HO[rloc][cs];
                    cc_store16(&VF[(((size_t)(g * 2 + mt) * 16 + s) * 64 +
                                    ((crow0 + ri) + 16 * (cs >> 3))) * 8 + (cs & 7)],
                               (_Float16)vv);
                }
            }
        }

        // ---- barrier 1: v published (stores drained by vmcnt + barrier) ----
        asm volatile("s_waitcnt vmcnt(0)" ::: "memory");
        __syncthreads();
        if (tid == 0) {
            __hip_atomic_fetch_add(flag, 1u, __ATOMIC_RELAXED, __HIP_MEMORY_SCOPE_AGENT);
            unsigned int tgt = (unsigned int)(2 * t + 1) * NS;
            while (__hip_atomic_load(flag, __ATOMIC_RELAXED, __HIP_MEMORY_SCOPE_AGENT) < tgt) {}
        }
        __syncthreads();

        // ================= phase B: hh_s, h update =================
        if (w < 4) {
            half8 vfr[16];
            {
                const _Float16* vf = &VF[(size_t)(g * 2 + mt) * 16 * 512];
                #pragma unroll
                for (int kt = 0; kt < 16; ++kt)
                    vfr[kt] = cc_load16(vf + kt * 512 + l * 8);
            }
            cc_wait();

            f32x4 acc2 = {0.f, 0.f, 0.f, 0.f};
            #pragma unroll
            for (int kt = 0; kt < 16; ++kt) {
                half8 bf = *(const half8*)&WB[nt2][kt][l][0];
                acc2 = __builtin_amdgcn_mfma_f32_16x16x32_f16(vfr[kt], bf, acc2, 0, 0, 0);
            }
            #pragma unroll
            for (int kf = 0; kf < 4; ++kf) {
                half8 bf = *(const half8*)&WB[nt2][16 + kf][l][0];
                acc2 = __builtin_amdgcn_mfma_f32_16x16x32_f16(xf[kf], bf, acc2, 0, 0, 0);
            }
            #pragma unroll
            for (int ri = 0; ri < 4; ++ri) {
                float pre = acc2[ri] + biasB;
                float e  = __expf(2.f * pre);
                float hh = 1.f - 2.f / (e + 1.f);          // tanh(pre)
                int rloc = mt * 16 + crow0 + ri;
                int cs = nt2 * 16 + m;
                float zz = zreg[ri];
                float ho = HO[rloc][cs];
                float hn = zz * ho + (1.f - zz) * hh;
                HO[rloc][cs] = hn;
                cc_store16(&HF[(((size_t)(g * 2 + mt) * 16 + s) * 64 +
                                ((crow0 + ri) + 16 * (cs >> 3))) * 8 + (cs & 7)],
                           (_Float16)hn);
            }
        }

        // ---- barrier 2: h' published ----
        asm volatile("s_waitcnt vmcnt(0)" ::: "memory");
        __syncthreads();
        if (tid == 0) {
            __hip_atomic_fetch_add(flag, 1u, __ATOMIC_RELAXED, __HIP_MEMORY_SCOPE_AGENT);
            unsigned int tgt = (unsigned int)(2 * t + 2) * NS;
            while (__hip_atomic_load(flag, __ATOMIC_RELAXED, __HIP_MEMORY_SCOPE_AGENT) < tgt) {}
        }
        __syncthreads();
    }

    // ---- write final h (own slice, f32) ----
    for (int i = tid; i < RG * SC; i += 512) {
        int r = i >> 5, c = i & 31;
        hout[(size_t)(g * RG + r) * HID + s * SC + c] = HO[r][c];
    }
}

// ---------------------------------------------------------------------------
// Head kernels (unchanged — fp32, proven correct)
// ---------------------------------------------------------------------------
__global__ __launch_bounds__(256) void maxout_k(
    const float* __restrict__ h, const float* __restrict__ moW,
    const float* __restrict__ mob, float* __restrict__ m)
{
    const int ot = blockIdx.x, bt = blockIdx.y;
    __shared__ float sA[32][33];
    __shared__ float sB[4][32][33];
    const int tid = threadIdx.x;
    const int tx = tid & 15, ty = tid >> 4;
    const int b0 = bt * 32, o0 = ot * 32;
    const int lr = tid >> 3, lk4 = (tid & 7) << 2;

    float acc[4][2][2];
    #pragma unroll
    for (int p = 0; p < 4; ++p)
        acc[p][0][0] = acc[p][0][1] = acc[p][1][0] = acc[p][1][1] = 0.f;

    for (int kt = 0; kt < 16; ++kt) {
        const int k0 = kt * 32;
        float4 a = *reinterpret_cast<const float4*>(&h[(b0 + lr) * HID + k0 + lk4]);
        float4 wv[4];
        #pragma unroll
        for (int p = 0; p < 4; ++p)
            wv[p] = *reinterpret_cast<const float4*>(&moW[((size_t)p * HID + k0 + lr) * MID + o0 + lk4]);
        __syncthreads();
        sA[lk4+0][lr] = a.x; sA[lk4+1][lr] = a.y; sA[lk4+2][lr] = a.z; sA[lk4+3][lr] = a.w;
        #pragma unroll
        for (int p = 0; p < 4; ++p) {
            sB[p][lr][lk4+0] = wv[p].x; sB[p][lr][lk4+1] = wv[p].y;
            sB[p][lr][lk4+2] = wv[p].z; sB[p][lr][lk4+3] = wv[p].w;
        }
        __syncthreads();
        #pragma unroll
        for (int kk = 0; kk < 32; ++kk) {
            float a0 = sA[kk][ty*2], a1 = sA[kk][ty*2+1];
            #pragma unroll
            for (int p = 0; p < 4; ++p) {
                float w0 = sB[p][kk][tx*2], w1 = sB[p][kk][tx*2+1];
                acc[p][0][0] += a0*w0; acc[p][0][1] += a0*w1;
                acc[p][1][0] += a1*w0; acc[p][1][1] += a1*w1;
            }
        }
    }

    #pragma unroll
    for (int q = 0; q < 2; ++q)
        #pragma unroll
        for (int c = 0; c < 2; ++c) {
            const int row = b0 + ty*2 + q, col = o0 + tx*2 + c;
            float best = -1e30f;
            #pragma unroll
            for (int p = 0; p < 4; ++p)
                best = fmaxf(best, acc[p][q][c] + mob[p * MID + col]);
            m[row * MID + col] = best;
        }
}

__global__ __launch_bounds__(256) void dense1_k(
    const float* __restrict__ m, const float* __restrict__ W,
    const float* __restrict__ b, float* __restrict__ a1)
{
    const int jt = blockIdx.x, bt = blockIdx.y;
    __shared__ float sA[32][33];
    __shared__ float sB[32][33];
    const int tid = threadIdx.x;
    const int tx = tid & 15, ty = tid >> 4;
    const int b0 = bt * 32, j0 = jt * 32;
    const int lr = tid >> 3, lk4 = (tid & 7) << 2;

    float acc[2][2] = {{0.f,0.f},{0.f,0.f}};

    for (int kt = 0; kt < 8; ++kt) {
        const int k0 = kt * 32;
        float4 a  = *reinterpret_cast<const float4*>(&m[(b0 + lr) * MID + k0 + lk4]);
        float4 bv = *reinterpret_cast<const float4*>(&W[(k0 + lr) * MID + j0 + lk4]);
        __syncthreads();
        sA[lk4+0][lr] = a.x; sA[lk4+1][lr] = a.y; sA[lk4+2][lr] = a.z; sA[lk4+3][lr] = a.w;
        sB[lr][lk4+0] = bv.x; sB[lr][lk4+1] = bv.y; sB[lr][lk4+2] = bv.z; sB[lr][lk4+3] = bv.w;
        __syncthreads();
        #pragma unroll
        for (int kk = 0; kk < 32; ++kk) {
            float a0 = sA[kk][ty*2], a1v = sA[kk][ty*2+1];
            float w0 = sB[kk][tx*2], w1 = sB[kk][tx*2+1];
            acc[0][0] += a0*w0; acc[0][1] += a0*w1;
            acc[1][0] += a1v*w0; acc[1][1] += a1v*w1;
        }
    }

    #pragma unroll
    for (int q = 0; q < 2; ++q)
        #pragma unroll
        for (int c = 0; c < 2; ++c) {
            const int row = b0 + ty*2 + q, col = j0 + tx*2 + c;
            a1[row * MID + col] = acc[q][c] + b[col];
        }
}

__global__ __launch_bounds__(256) void highway_k(
    const float* __restrict__ a1,
    const float* __restrict__ hwW, const float* __restrict__ hwb,
    const float* __restrict__ hwWc, const float* __restrict__ hwbc,
    float* __restrict__ h2)
{
    const int jt = blockIdx.x, bt = blockIdx.y;
    __shared__ float sA[32][33];
    __shared__ float sBh[32][33];
    __shared__ float sBc[32][33];
    const int tid = threadIdx.x;
    const int tx = tid & 15, ty = tid >> 4;
    const int b0 = bt * 32, j0 = jt * 32;
    const int lr = tid >> 3, lk4 = (tid & 7) << 2;

    float acch[2][2] = {{0.f,0.f},{0.f,0.f}};
    float accc[2][2] = {{0.f,0.f},{0.f,0.f}};

    for (int kt = 0; kt < 8; ++kt) {
        const int k0 = kt * 32;
        float4 a   = *reinterpret_cast<const float4*>(&a1[(b0 + lr) * MID + k0 + lk4]);
        float4 bh4 = *reinterpret_cast<const float4*>(&hwW[(k0 + lr) * MID + j0 + lk4]);
        float4 bc4 = *reinterpret_cast<const float4*>(&hwWc[(k0 + lr) * MID + j0 + lk4]);
        __syncthreads();
        sA[lk4+0][lr] = a.x; sA[lk4+1][lr] = a.y; sA[lk4+2][lr] = a.z; sA[lk4+3][lr] = a.w;
        sBh[lr][lk4+0] = bh4.x; sBh[lr][lk4+1] = bh4.y; sBh[lr][lk4+2] = bh4.z; sBh[lr][lk4+3] = bh4.w;
        sBc[lr][lk4+0] = bc4.x; sBc[lr][lk4+1] = bc4.y; sBc[lr][lk4+2] = bc4.z; sBc[lr][lk4+3] = bc4.w;
        __syncthreads();
        #pragma unroll
        for (int kk = 0; kk < 32; ++kk) {
            float a0 = sA[kk][ty*2], a1v = sA[kk][ty*2+1];
            float h0 = sBh[kk][tx*2], h1 = sBh[kk][tx*2+1];
            float c0 = sBc[kk][tx*2], c1 = sBc[kk][tx*2+1];
            acch[0][0] += a0*h0; acch[0][1] += a0*h1;
            acch[1][0] += a1v*h0; acch[1][1] += a1v*h1;
            accc[0][0] += a0*c0; accc[0][1] += a0*c1;
            accc[1][0] += a1v*c0; accc[1][1] += a1v*c1;
        }
    }

    #pragma unroll
    for (int q = 0; q < 2; ++q)
        #pragma unroll
        for (int c = 0; c < 2; ++c) {
            const int row = b0 + ty*2 + q, col = j0 + tx*2 + c;
            float tt = 1.f / (1.f + expf(-(accc[q][c] + hwbc[col])));
            float hp = fmaxf(acch[q][c] + hwb[col], 0.f);
            float av = a1[row * MID + col];
            h2[row * MID + col] = tt * hp + (1.f - tt) * av;
        }
}

__global__ __launch_bounds__(256) void d2_softmax(
    const float* __restrict__ h2, const float* __restrict__ W,
    const float* __restrict__ b, float* __restrict__ out)
{
    const int b0 = blockIdx.x * 16;
    const int r = threadIdx.x >> 4, c = threadIdx.x & 15;
    const int row = b0 + r;

    float acc = b[c];
    for (int i = 0; i < MID; ++i)
        acc += h2[row * MID + i] * W[i * NCLS + c];

    float mx = acc;
    #pragma unroll
    for (int off = 8; off; off >>= 1)
        mx = fmaxf(mx, __shfl_xor(mx, off, 16));
    float e = expf(acc - mx);
    float sm = e;
    #pragma unroll
    for (int off = 8; off; off >>= 1)
        sm += __shfl_xor(sm, off, 16);
    out[row * NCLS + c] = e / sm;
}

// ---------------------------------------------------------------------------
extern "C" void kernel_launch(void* const* d_in, const int* in_sizes, int n_in,
                              void* d_out, int out_size, void* d_ws, size_t ws_size,
                              hipStream_t stream) {
    (void)in_sizes; (void)n_in; (void)out_size; (void)ws_size;

    const float* x    = (const float*)d_in[0];
    const float* Wz   = (const float*)d_in[1];
    const float* Wr   = (const float*)d_in[2];
    const float* Wh   = (const float*)d_in[3];
    const float* Uz   = (const float*)d_in[4];
    const float* Ur   = (const float*)d_in[5];
    const float* Uh   = (const float*)d_in[6];
    const float* bz   = (const float*)d_in[7];
    const float* br   = (const float*)d_in[8];
    const float* bh   = (const float*)d_in[9];
    const float* moW  = (const float*)d_in[10];
    const float* mob  = (const float*)d_in[11];
    const float* d1W  = (const float*)d_in[12];
    const float* d1b  = (const float*)d_in[13];
    const float* hwW  = (const float*)d_in[14];
    const float* hwb  = (const float*)d_in[15];
    const float* hwWc = (const float*)d_in[16];
    const float* hwbc = (const float*)d_in[17];
    const float* d2W  = (const float*)d_in[18];
    const float* d2b  = (const float*)d_in[19];
    float* out = (float*)d_out;

    char* ws = (char*)d_ws;
    _Float16* GWA = (_Float16*)(ws + 0);              // 1,310,720 B
    _Float16* GWB = (_Float16*)(ws + 1310720);        //   655,360 B
    _Float16* HF  = (_Float16*)(ws + 1966080);        //   262,144 B
    _Float16* VF  = (_Float16*)(ws + 2228224);        //   262,144 B
    unsigned int* cnt = (unsigned int*)(ws + 2490368);//     1,024 B
    float*    hbuf = (float*)(ws + 2491392);          //   524,288 B
    // head temps overlap the GWA region (head runs strictly after gru_sync):
    float*    mxb = (float*)(ws + 0);                 //   262,144 B
    float*    a1b = (float*)(ws + 262144);            //   262,144 B
    float*    h2b = (float*)(ws + 524288);            //   262,144 B

    hipMemsetAsync(HF, 0, 262144, stream);
    hipMemsetAsync(cnt, 0, 1024, stream);

    pack_wA<<<2560, 256, 0, stream>>>(Uz, Ur, Wz, Wr, GWA);
    pack_wB<<<1280, 256, 0, stream>>>(Uh, Wh, GWB);

    gru_sync<<<128, 512, 0, stream>>>(x, GWA, GWB, bz, br, bh, HF, VF, cnt, hbuf);

    dim3 blk(256);
    maxout_k<<<dim3(8, 8), blk, 0, stream>>>(hbuf, moW, mob, mxb);
    dense1_k<<<dim3(8, 8), blk, 0, stream>>>(mxb, d1W, d1b, a1b);
    highway_k<<<dim3(8, 8), blk, 0, stream>>>(a1b, hwW, hwb, hwWc, hwbc, h2b);
    d2_softmax<<<16, blk, 0, stream>>>(h2b, d2W, d2b, out);
}